// Round 6
// baseline (173.819 us; speedup 1.0000x reference)
//
#include <hip/hip_runtime.h>

#define B_  32
#define CL_ 1024
#define QL_ 512
#define D_  256

typedef _Float16 f16;
typedef __attribute__((ext_vector_type(2))) _Float16 f16x2;
typedef __attribute__((ext_vector_type(4))) _Float16 f16x4;
typedef __attribute__((ext_vector_type(8))) _Float16 f16x8;
typedef __attribute__((ext_vector_type(4))) float    f32x4;

// ------- K0: q -> f16 (q_h), qT_h transpose, sqv[b,j] = q.w_q — fused ----
__global__ __launch_bounds__(256) void k0_prep(const float* __restrict__ q,
                                               const float* __restrict__ w_q,
                                               f16* __restrict__ q_h,
                                               f16* __restrict__ qT_h,
                                               float* __restrict__ sqv) {
  __shared__ f16 q_l[64][258];                 // +2 pad: row stride 516B
  int b = blockIdx.y, j0 = blockIdx.x * 64, tid = threadIdx.x;
  int r = tid >> 2, seg = tid & 3;             // row j0+r, d-quarter seg
  const float* qrow = q   + ((size_t)(b * QL_ + j0 + r)) * D_ + seg * 64;
  f16*        qhrow = q_h + ((size_t)(b * QL_ + j0 + r)) * D_ + seg * 64;
  float dot = 0.f;
  #pragma unroll
  for (int u = 0; u < 16; ++u) {
    f32x4 v  = *(const f32x4*)(qrow + 4 * u);
    f32x4 wv = *(const f32x4*)(w_q + seg * 64 + 4 * u);
    f16x4 h;
    h[0] = (f16)v[0]; h[1] = (f16)v[1]; h[2] = (f16)v[2]; h[3] = (f16)v[3];
    *(f16x4*)(&q_l[r][seg * 64 + 4 * u]) = h;
    *(f16x4*)(qhrow + 4 * u) = h;
    dot += v[0]*wv[0] + v[1]*wv[1] + v[2]*wv[2] + v[3]*wv[3];
  }
  dot += __shfl_xor(dot, 1, 64);
  dot += __shfl_xor(dot, 2, 64);
  if (seg == 0) sqv[b * QL_ + j0 + r] = dot;
  __syncthreads();
  f16* qTb = qT_h + (size_t)b * D_ * QL_ + j0;
  #pragma unroll
  for (int s = 0; s < 32; ++s) {
    int e = tid + 256 * s;                     // 256 d x 32 j-pairs
    int d = e >> 5, j2 = (e & 31) * 2;
    f16x2 p;
    p[0] = q_l[j2][d];
    p[1] = q_l[j2 + 1][d];
    *(f16x2*)(qTb + (size_t)d * QL_ + j2) = p;
  }
}

// ------- K1a: scores + softmax -> normalized P (f16) + mrow --------------
// 16 i-rows x 512 j per block, 256 thr = 4 waves (wave w: j in [128w,128w+128)).
// ~13 KB LDS, big grid: high TLP, no multi-phase convoy.
__global__ __launch_bounds__(256, 4) void k1a_scores(
    const float* __restrict__ c, const f16* __restrict__ q_h,
    const float* __restrict__ sqv, const float* __restrict__ w_c,
    const float* __restrict__ w_cq, f16* __restrict__ Pg,
    float* __restrict__ mrow, int b_base, int bpx, int ng)
{
  __shared__ f16 cw_t[16][264];
  __shared__ float sqv_l[512];
  __shared__ float wcq_l[256], wc_l[256], scv_l[16];
  __shared__ float red[4][16];
  __shared__ float mf[16], lf[16];

  const int tid = threadIdx.x;
  const int w = tid >> 6, l = tid & 63, g = l >> 4, l15 = l & 15;
  int b, i0;
  {
    int lin = blockIdx.x;
    if (ng <= 4) {                      // XCD-swizzled (round-robin mapping)
      int xcd = lin & 7, slot = lin >> 3;
      b = b_base + xcd * bpx + (slot >> 6);
      i0 = (slot & 63) << 4;
    } else {
      b = b_base + (lin >> 6);
      i0 = (lin & 63) << 4;
    }
  }
  const int bl = b - b_base;

  wcq_l[tid] = w_cq[tid & 255]; wc_l[tid] = w_c[tid & 255];
  sqv_l[tid] = sqv[b * QL_ + tid];
  sqv_l[tid + 256] = sqv[b * QL_ + tid + 256];
  __syncthreads();

  // stage cw_t = f16(c * w_cq); scv = c . w_c
  {
    int r = tid >> 4, seg = tid & 15;
    const float* crow = c + (size_t)(b * CL_ + i0 + r) * D_;
    float dot = 0.f;
    #pragma unroll
    for (int u = 0; u < 4; ++u) {
      int d = seg * 16 + u * 4;
      f32x4 v  = *(const f32x4*)(crow + d);
      f32x4 wv = *(const f32x4*)(wcq_l + d);
      f32x4 w2 = *(const f32x4*)(wc_l + d);
      f16x4 h;
      h[0] = (f16)(v[0]*wv[0]); h[1] = (f16)(v[1]*wv[1]);
      h[2] = (f16)(v[2]*wv[2]); h[3] = (f16)(v[3]*wv[3]);
      *(f16x4*)(&cw_t[r][d]) = h;
      dot += v[0]*w2[0] + v[1]*w2[1] + v[2]*w2[2] + v[3]*w2[3];
    }
    dot += __shfl_xor(dot, 1, 64); dot += __shfl_xor(dot, 2, 64);
    dot += __shfl_xor(dot, 4, 64); dot += __shfl_xor(dot, 8, 64);
    if (seg == 0) scv_l[r] = dot;
  }
  __syncthreads();

  // scores U = cw @ q^T for 16 rows x this wave's 128 j
  f32x4 acc[8];
  #pragma unroll
  for (int fj = 0; fj < 8; ++fj) acc[fj] = (f32x4){0.f,0.f,0.f,0.f};
  const f16* qbase = q_h + (size_t)b * QL_ * D_
                   + (size_t)(128 * w + l15) * D_ + 8 * g;
  #pragma unroll
  for (int dk = 0; dk < 8; ++dk) {
    f16x8 a0 = *(const f16x8*)(&cw_t[l15][dk * 32 + 8 * g]);
    #pragma unroll
    for (int fj = 0; fj < 8; ++fj) {
      f16x8 bf = *(const f16x8*)(qbase + (size_t)(16 * fj) * D_ + dk * 32);
      acc[fj] = __builtin_amdgcn_mfma_f32_16x16x32_f16(a0, bf, acc[fj], 0, 0, 0);
    }
  }

  // softmax over j (512 per row); rows il = 4g + r
  #pragma unroll
  for (int r = 0; r < 4; ++r) {
    float mx = -1e30f;
    #pragma unroll
    for (int fj = 0; fj < 8; ++fj) {
      float v = acc[fj][r] + sqv_l[128 * w + 16 * fj + l15];
      acc[fj][r] = v;
      mx = fmaxf(mx, v);
    }
    mx = fmaxf(mx, __shfl_xor(mx, 1, 64));
    mx = fmaxf(mx, __shfl_xor(mx, 2, 64));
    mx = fmaxf(mx, __shfl_xor(mx, 4, 64));
    mx = fmaxf(mx, __shfl_xor(mx, 8, 64));
    if (l15 == 0) red[w][4 * g + r] = mx;
  }
  __syncthreads();
  if (tid < 16) {
    float m = fmaxf(fmaxf(red[0][tid], red[1][tid]),
                    fmaxf(red[2][tid], red[3][tid]));
    mf[tid] = m;
    mrow[b * CL_ + i0 + tid] = m + scv_l[tid];
  }
  __syncthreads();
  #pragma unroll
  for (int r = 0; r < 4; ++r) {
    float mv = mf[4 * g + r];
    float s = 0.f;
    #pragma unroll
    for (int fj = 0; fj < 8; ++fj) {
      float p = __expf(acc[fj][r] - mv);
      acc[fj][r] = p;
      s += p;
    }
    s += __shfl_xor(s, 1, 64); s += __shfl_xor(s, 2, 64);
    s += __shfl_xor(s, 4, 64); s += __shfl_xor(s, 8, 64);
    if (l15 == 0) red[w][4 * g + r] = s;
  }
  __syncthreads();
  if (tid < 16)
    lf[tid] = 1.0f / (red[0][tid] + red[1][tid] + red[2][tid] + red[3][tid]);
  __syncthreads();

  // store normalized P (f16)
  f16* Pb = Pg + (size_t)bl * CL_ * QL_;
  #pragma unroll
  for (int r = 0; r < 4; ++r) {
    float inv = lf[4 * g + r];
    f16* prow = Pb + (size_t)(i0 + 4 * g + r) * QL_ + 128 * w + l15;
    #pragma unroll
    for (int fj = 0; fj < 8; ++fj)
      prow[16 * fj] = (f16)(acc[fj][r] * inv);
  }
}

// ------- K1b: c2q = P @ q (per-batch GEMM) + epilogue --------------------
// 64x64 output tile, 256 thr = 4 waves (wave = 32x32 subtile), K=512.
__global__ __launch_bounds__(256, 4) void k1b_pv(
    const float* __restrict__ c, const f16* __restrict__ Pg,
    const f16* __restrict__ qT_h, float* __restrict__ out,
    int b_base, int bpx, int ng)
{
  __shared__ float o_l[64][68];
  const int tid = threadIdx.x;
  const int w = tid >> 6, l = tid & 63, g = l >> 4, l15 = l & 15;
  int b, rem;
  {
    int lin = blockIdx.x;
    if (ng <= 4) {
      int xcd = lin & 7, slot = lin >> 3;
      b = b_base + xcd * bpx + (slot >> 6);
      rem = slot & 63;
    } else {
      b = b_base + (lin >> 6);
      rem = lin & 63;
    }
  }
  const int bl = b - b_base;
  const int i0 = (rem >> 2) * 64, d0 = (rem & 3) * 64;
  const int wi = w >> 1, wd = w & 1;

  const f16* a0p = Pg + (size_t)bl * CL_ * QL_
                 + (size_t)(i0 + 32 * wi + l15) * QL_ + 8 * g;
  const f16* a1p = a0p + 16 * QL_;
  const f16* b0p = qT_h + (size_t)b * D_ * QL_
                 + (size_t)(d0 + 32 * wd + l15) * QL_ + 8 * g;
  const f16* b1p = b0p + 16 * QL_;

  f32x4 acc[2][2];
  acc[0][0] = (f32x4){0.f,0.f,0.f,0.f}; acc[0][1] = acc[0][0];
  acc[1][0] = acc[0][0];                acc[1][1] = acc[0][0];
  #pragma unroll
  for (int kt = 0; kt < 16; ++kt) {
    f16x8 a0 = *(const f16x8*)(a0p + kt * 32);
    f16x8 a1 = *(const f16x8*)(a1p + kt * 32);
    f16x8 b0 = *(const f16x8*)(b0p + kt * 32);
    f16x8 b1 = *(const f16x8*)(b1p + kt * 32);
    acc[0][0] = __builtin_amdgcn_mfma_f32_16x16x32_f16(a0, b0, acc[0][0], 0, 0, 0);
    acc[0][1] = __builtin_amdgcn_mfma_f32_16x16x32_f16(a0, b1, acc[0][1], 0, 0, 0);
    acc[1][0] = __builtin_amdgcn_mfma_f32_16x16x32_f16(a1, b0, acc[1][0], 0, 0, 0);
    acc[1][1] = __builtin_amdgcn_mfma_f32_16x16x32_f16(a1, b1, acc[1][1], 0, 0, 0);
  }

  #pragma unroll
  for (int fi = 0; fi < 2; ++fi)
    #pragma unroll
    for (int fd = 0; fd < 2; ++fd)
      #pragma unroll
      for (int r = 0; r < 4; ++r)
        o_l[32 * wi + 16 * fi + 4 * g + r][32 * wd + 16 * fd + l15] = acc[fi][fd][r];
  __syncthreads();

  #pragma unroll
  for (int s = 0; s < 4; ++s) {
    int chunk = tid + 256 * s;                 // 64 rows x 16 f32x4
    int row = chunk >> 4, col = (chunk & 15) * 4;
    size_t rowoff = (size_t)(b * CL_ + i0 + row);
    f32x4 c2q = *(const f32x4*)(&o_l[row][col]);
    f32x4 cv  = *(const f32x4*)(c + rowoff * D_ + d0 + col);
    f32x4 prod;
    prod[0] = cv[0]*c2q[0]; prod[1] = cv[1]*c2q[1];
    prod[2] = cv[2]*c2q[2]; prod[3] = cv[3]*c2q[3];
    float* ob = out + rowoff * (4 * D_) + d0 + col;
    *(f32x4*)(ob)            = cv;
    *(f32x4*)(ob + D_)       = c2q;
    *(f32x4*)(ob + 2 * D_)   = prod;
  }
}

// ------- K2a: bvec[b,:] = softmax_i(mrow[b,:]) ---------------------------
__global__ __launch_bounds__(256) void k2a_bvec(const float* __restrict__ mrow,
                                                float* __restrict__ bvec) {
  __shared__ float red[256];
  int b = blockIdx.x, tid = threadIdx.x;
  f32x4 v = *(const f32x4*)(mrow + b * CL_ + tid * 4);
  float mx = fmaxf(fmaxf(v[0], v[1]), fmaxf(v[2], v[3]));
  red[tid] = mx;
  __syncthreads();
  for (int s = 128; s > 0; s >>= 1) {
    if (tid < s) red[tid] = fmaxf(red[tid], red[tid + s]);
    __syncthreads();
  }
  float gmx = red[0];
  __syncthreads();
  f32x4 e;
  e[0] = __expf(v[0] - gmx); e[1] = __expf(v[1] - gmx);
  e[2] = __expf(v[2] - gmx); e[3] = __expf(v[3] - gmx);
  red[tid] = e[0] + e[1] + e[2] + e[3];
  __syncthreads();
  for (int s = 128; s > 0; s >>= 1) {
    if (tid < s) red[tid] += red[tid + s];
    __syncthreads();
  }
  float inv = 1.0f / red[0];
  e[0] *= inv; e[1] *= inv; e[2] *= inv; e[3] *= inv;
  *(f32x4*)(bvec + b * CL_ + tid * 4) = e;
}

// ------- K2b: part[b,ch,:] = sum_{i in chunk} bvec[i] * c[i,:] -----------
__global__ __launch_bounds__(256) void k2b_part(const float* __restrict__ c,
                                                const float* __restrict__ bvec,
                                                float* __restrict__ part) {
  __shared__ f32x4 pl[4][64];
  int ch = blockIdx.x, b = blockIdx.y, tid = threadIdx.x;
  int ro = tid >> 6, dl = tid & 63;
  const float* cb = c + ((size_t)b * CL_ + ch * 128) * D_;
  const float* bv = bvec + b * CL_ + ch * 128;
  f32x4 acc = (f32x4){0.f, 0.f, 0.f, 0.f};
  for (int i = ro; i < 128; i += 4) {
    float wgt = bv[i];
    f32x4 v = *(const f32x4*)(cb + (size_t)i * D_ + dl * 4);
    acc[0] += wgt * v[0]; acc[1] += wgt * v[1];
    acc[2] += wgt * v[2]; acc[3] += wgt * v[3];
  }
  pl[ro][dl] = acc;
  __syncthreads();
  if (tid < 64) {
    f32x4 s = (pl[0][tid] + pl[1][tid]) + (pl[2][tid] + pl[3][tid]);
    *(f32x4*)(part + ((size_t)(b * 8 + ch)) * D_ + tid * 4) = s;
  }
}

// ------- K2c: q2c[b,:] = sum_ch part[b,ch,:] -----------------------------
__global__ __launch_bounds__(256) void k2c_red(const float* __restrict__ part,
                                               float* __restrict__ q2c) {
  int b = blockIdx.x, d = threadIdx.x;
  float s = 0.f;
  #pragma unroll
  for (int ch = 0; ch < 8; ++ch) s += part[((size_t)(b * 8 + ch)) * D_ + d];
  q2c[b * D_ + d] = s;
}

// ------- K3: out[3D:4D] = c * q2c (broadcast) ----------------------------
__global__ __launch_bounds__(256) void k3_tail(const float* __restrict__ c,
                                               const float* __restrict__ q2c,
                                               float* __restrict__ out) {
  size_t idx = (size_t)blockIdx.x * 256 + threadIdx.x;   // B*CL*64 float4s
  int b   = (int)(idx >> 16);
  int rem = (int)(idx & 65535);
  int i = rem >> 6, d4 = (rem & 63) * 4;
  f32x4 cv = *(const f32x4*)(c + (size_t)(b * CL_ + i) * D_ + d4);
  f32x4 gv = *(const f32x4*)(q2c + b * D_ + d4);
  f32x4 r;
  r[0] = cv[0]*gv[0]; r[1] = cv[1]*gv[1]; r[2] = cv[2]*gv[2]; r[3] = cv[3]*gv[3];
  *(f32x4*)(out + (size_t)(b * CL_ + i) * (4 * D_) + 3 * D_ + d4) = r;
}

extern "C" void kernel_launch(void* const* d_in, const int* in_sizes, int n_in,
                              void* d_out, int out_size, void* d_ws, size_t ws_size,
                              hipStream_t stream) {
  const float* c    = (const float*)d_in[0];
  const float* q    = (const float*)d_in[1];
  const float* w_c  = (const float*)d_in[2];
  const float* w_q  = (const float*)d_in[4];
  const float* w_cq = (const float*)d_in[6];
  float* out = (float*)d_out;
  char* ws = (char*)d_ws;
  f16*   q_h  = (f16*)ws;                       //  8,388,608 B
  f16*   qT_h = (f16*)(ws + 8388608);           //  8,388,608 B
  float* sqv  = (float*)(ws + 16777216);        //     65,536 B
  float* mrow = (float*)(ws + 16842752);        //    131,072 B
  float* bvec = (float*)(ws + 16973824);        //    131,072 B
  float* part = (float*)(ws + 17104896);        //    262,144 B
  float* q2c  = (float*)(ws + 17367040);        //     32,768 B
  const size_t pbase = 17399808;
  // P buffer (f16, normalized): full = 33.5 MB; split into batch-groups if
  // ws is smaller. Stream order makes group reuse race-free.
  int ng = 1;
  while (ng < 32 && pbase + (33554432ull / ng) > ws_size) ng <<= 1;
  f16* Pg = (f16*)(ws + pbase);
  const int bpg = 32 / ng;                       // batches per group
  const int bpx = (ng <= 4) ? (4 / ng) : 0;      // batches per XCD (swizzle)
  const int nb  = bpg * 64;                      // blocks per launch

  hipLaunchKernelGGL(k0_prep, dim3(8, 32), dim3(256), 0, stream,
                     q, w_q, q_h, qT_h, sqv);
  for (int gI = 0; gI < ng; ++gI) {
    hipLaunchKernelGGL(k1a_scores, dim3(nb), dim3(256), 0, stream,
                       c, q_h, sqv, w_c, w_cq, Pg, mrow, gI * bpg, bpx, ng);
    hipLaunchKernelGGL(k1b_pv, dim3(nb), dim3(256), 0, stream,
                       c, Pg, qT_h, out, gI * bpg, bpx, ng);
  }
  hipLaunchKernelGGL(k2a_bvec, dim3(32),    dim3(256), 0, stream, mrow, bvec);
  hipLaunchKernelGGL(k2b_part, dim3(8, 32), dim3(256), 0, stream, c, bvec, part);
  hipLaunchKernelGGL(k2c_red,  dim3(32),    dim3(256), 0, stream, part, q2c);
  hipLaunchKernelGGL(k3_tail,  dim3(8192),  dim3(256), 0, stream, c, q2c, out);
}

// Round 7
// 99.548 us; speedup vs baseline: 1.7461x; 1.7461x over previous
//
#include <hip/hip_runtime.h>

#define B_  32
#define CL_ 1024
#define QL_ 512
#define D_  256

typedef _Float16 f16;
typedef __attribute__((ext_vector_type(2))) _Float16 f16x2;
typedef __attribute__((ext_vector_type(4))) _Float16 f16x4;
typedef __attribute__((ext_vector_type(8))) _Float16 f16x8;
typedef __attribute__((ext_vector_type(4))) float    f32x4;

// ------- K0: q -> f16 (q_h), qT_h transpose, sqv[b,j] = q.w_q — fused ----
__global__ __launch_bounds__(256) void k0_prep(const float* __restrict__ q,
                                               const float* __restrict__ w_q,
                                               f16* __restrict__ q_h,
                                               f16* __restrict__ qT_h,
                                               float* __restrict__ sqv) {
  __shared__ f16 q_l[64][258];
  int b = blockIdx.y, j0 = blockIdx.x * 64, tid = threadIdx.x;
  int r = tid >> 2, seg = tid & 3;
  const float* qrow = q   + ((size_t)(b * QL_ + j0 + r)) * D_ + seg * 64;
  f16*        qhrow = q_h + ((size_t)(b * QL_ + j0 + r)) * D_ + seg * 64;
  float dot = 0.f;
  #pragma unroll
  for (int u = 0; u < 16; ++u) {
    f32x4 v  = *(const f32x4*)(qrow + 4 * u);
    f32x4 wv = *(const f32x4*)(w_q + seg * 64 + 4 * u);
    f16x4 h;
    h[0] = (f16)v[0]; h[1] = (f16)v[1]; h[2] = (f16)v[2]; h[3] = (f16)v[3];
    *(f16x4*)(&q_l[r][seg * 64 + 4 * u]) = h;
    *(f16x4*)(qhrow + 4 * u) = h;
    dot += v[0]*wv[0] + v[1]*wv[1] + v[2]*wv[2] + v[3]*wv[3];
  }
  dot += __shfl_xor(dot, 1, 64);
  dot += __shfl_xor(dot, 2, 64);
  if (seg == 0) sqv[b * QL_ + j0 + r] = dot;
  __syncthreads();
  f16* qTb = qT_h + (size_t)b * D_ * QL_ + j0;
  #pragma unroll
  for (int s = 0; s < 32; ++s) {
    int e = tid + 256 * s;
    int d = e >> 5, j2 = (e & 31) * 2;
    f16x2 p;
    p[0] = q_l[j2][d];
    p[1] = q_l[j2 + 1][d];
    *(f16x2*)(qTb + (size_t)d * QL_ + j2) = p;
  }
}

// ------- K1 fused, BM=128: scores + softmax + PV + epilogue --------------
// 512 thr = 8 waves. Phase A: wave w owns j-slice [64w,64w+64), all 128 rows;
// A(cw) staged ONCE in LDS -> q read once per BLOCK (64 MB total, was 512).
// P kept in 128KB swizzled LDS tile (no global round-trip). Phase C: wave w
// owns d-slice [32w,32w+32). o through LDS -> coalesced f32x4 stores.
__global__ __launch_bounds__(512, 2) void k1_fused(
    const float* __restrict__ c, const f16* __restrict__ q_h,
    const f16* __restrict__ qT_h, const float* __restrict__ sqv,
    const float* __restrict__ w_c, const float* __restrict__ w_cq,
    float* __restrict__ out, float* __restrict__ mrow)
{
  __shared__ alignas(16) char smem[142848];
  f16 (*cw_t)[264]  = (f16 (*)[264])(smem);          // 67584 B (phase A)
  char* P_b         = smem;                          // 131072 B swizzled (B/C)
  float (*o_l)[260] = (float (*)[260])(smem);        // 133120 B (epilogue)
  float* sqv_l = (float*)(smem + 133120);            // 2048
  float* wcq_l = (float*)(smem + 135168);            // 1024
  float* wc_l  = (float*)(smem + 136192);            // 1024
  float* scv_l = (float*)(smem + 137216);            // 512
  float (*red)[128] = (float (*)[128])(smem + 137728); // 4096
  float* mf = (float*)(smem + 141824);               // 512
  float* lf = (float*)(smem + 142336);               // 512

  const int tid = threadIdx.x;
  const int w = tid >> 6, l = tid & 63, g = l >> 4, l15 = l & 15;
  const int lin = blockIdx.x, xcd = lin & 7, slot = lin >> 3;
  const int b  = xcd * 4 + (slot >> 3);              // 4 batches per XCD
  const int i0 = (slot & 7) * 128;

  if (tid < 256) { wcq_l[tid] = w_cq[tid]; wc_l[tid] = w_c[tid]; }
  sqv_l[tid] = sqv[b * QL_ + tid];
  __syncthreads();

  // ---- stage cw_t = f16(c * w_cq) (128 rows); scv = c . w_c ------------
  {
    int row = tid >> 2, seg = tid & 3;
    const float* crow = c + (size_t)(b * CL_ + i0 + row) * D_ + seg * 64;
    float dot = 0.f;
    #pragma unroll
    for (int u = 0; u < 16; ++u) {
      f32x4 v  = *(const f32x4*)(crow + 4 * u);
      f32x4 wv = *(const f32x4*)(wcq_l + seg * 64 + 4 * u);
      f32x4 w2 = *(const f32x4*)(wc_l  + seg * 64 + 4 * u);
      f16x4 h;
      h[0] = (f16)(v[0]*wv[0]); h[1] = (f16)(v[1]*wv[1]);
      h[2] = (f16)(v[2]*wv[2]); h[3] = (f16)(v[3]*wv[3]);
      *(f16x4*)(&cw_t[row][seg * 64 + 4 * u]) = h;
      dot += v[0]*w2[0] + v[1]*w2[1] + v[2]*w2[2] + v[3]*w2[3];
    }
    dot += __shfl_xor(dot, 1, 64); dot += __shfl_xor(dot, 2, 64);
    if (seg == 0) scv_l[row] = dot;
  }
  __syncthreads();

  // ---- Phase A: scores for 128 rows x this wave's 64 j -----------------
  f32x4 acc[8][4];
  #pragma unroll
  for (int fi = 0; fi < 8; ++fi)
    #pragma unroll
    for (int fj = 0; fj < 4; ++fj)
      acc[fi][fj] = (f32x4){0.f,0.f,0.f,0.f};

  const f16* qb = q_h + (size_t)b * QL_ * D_ + (size_t)(64 * w + l15) * D_ + 8 * g;
  #pragma unroll
  for (int dk = 0; dk < 8; ++dk) {
    f16x8 av[8];
    #pragma unroll
    for (int fi = 0; fi < 8; ++fi)
      av[fi] = *(const f16x8*)(&cw_t[16 * fi + l15][dk * 32 + 8 * g]);
    #pragma unroll
    for (int fj = 0; fj < 4; ++fj) {
      f16x8 bf = *(const f16x8*)(qb + (size_t)(16 * fj) * D_ + dk * 32);
      #pragma unroll
      for (int fi = 0; fi < 8; ++fi)
        acc[fi][fj] = __builtin_amdgcn_mfma_f32_16x16x32_f16(av[fi], bf, acc[fi][fj], 0, 0, 0);
    }
  }

  // ---- Phase B: softmax over j (cross-wave via red[8][128]) ------------
  #pragma unroll
  for (int fi = 0; fi < 8; ++fi) {
    #pragma unroll
    for (int r = 0; r < 4; ++r) {
      float mx = -1e30f;
      #pragma unroll
      for (int fj = 0; fj < 4; ++fj) {
        float v = acc[fi][fj][r] + sqv_l[64 * w + 16 * fj + l15];
        acc[fi][fj][r] = v;
        mx = fmaxf(mx, v);
      }
      mx = fmaxf(mx, __shfl_xor(mx, 1, 64));
      mx = fmaxf(mx, __shfl_xor(mx, 2, 64));
      mx = fmaxf(mx, __shfl_xor(mx, 4, 64));
      mx = fmaxf(mx, __shfl_xor(mx, 8, 64));
      if (l15 == 0) red[w][16 * fi + 4 * g + r] = mx;
    }
  }
  __syncthreads();
  if (tid < 128) {
    float m = red[0][tid];
    #pragma unroll
    for (int w2 = 1; w2 < 8; ++w2) m = fmaxf(m, red[w2][tid]);
    mf[tid] = m;
    mrow[b * CL_ + i0 + tid] = m + scv_l[tid];
  }
  __syncthreads();
  #pragma unroll
  for (int fi = 0; fi < 8; ++fi) {
    #pragma unroll
    for (int r = 0; r < 4; ++r) {
      float mv = mf[16 * fi + 4 * g + r];
      float s = 0.f;
      #pragma unroll
      for (int fj = 0; fj < 4; ++fj) {
        float p = __expf(acc[fi][fj][r] - mv);
        acc[fi][fj][r] = p;
        s += p;
      }
      s += __shfl_xor(s, 1, 64); s += __shfl_xor(s, 2, 64);
      s += __shfl_xor(s, 4, 64); s += __shfl_xor(s, 8, 64);
      if (l15 == 0) red[w][16 * fi + 4 * g + r] = s;
    }
  }
  __syncthreads();
  if (tid < 128) {
    float s = 0.f;
    #pragma unroll
    for (int w2 = 0; w2 < 8; ++w2) s += red[w2][tid];
    lf[tid] = 1.0f / s;
  }
  __syncthreads();   // cw_t dead from here; P_b may overwrite

  // ---- write normalized P into swizzled LDS tile -----------------------
  // elem (row, col): byte = (row<<10) + (col<<1), then ^= (row&7)<<4
  #pragma unroll
  for (int fi = 0; fi < 8; ++fi) {
    #pragma unroll
    for (int r = 0; r < 4; ++r) {
      int row = 16 * fi + 4 * g + r;
      float inv = lf[row];
      int rb = (row << 10) ^ ((row & 7) << 4);
      #pragma unroll
      for (int fj = 0; fj < 4; ++fj) {
        int byte = (rb ^ ((128 * w + 32 * fj + 2 * l15) & 0x70))
                 | ((128 * w + 32 * fj + 2 * l15) & ~0x70);
        *(f16*)(P_b + (((row << 10) + 128 * w + 32 * fj + 2 * l15) ^ ((row & 7) << 4)))
            = (f16)(acc[fi][fj][r] * inv);
        (void)byte;
      }
    }
  }
  __syncthreads();   // P visible to all waves

  // ---- Phase C: c2q = P @ qT; wave w owns d in [32w,32w+32) ------------
  f32x4 o[8][2];
  #pragma unroll
  for (int fi = 0; fi < 8; ++fi) { o[fi][0] = (f32x4){0.f,0.f,0.f,0.f}; o[fi][1] = o[fi][0]; }
  const f16* qTb = qT_h + (size_t)b * D_ * QL_ + (size_t)(32 * w + l15) * QL_ + 8 * g;
  #pragma unroll
  for (int jt = 0; jt < 16; ++jt) {
    f16x8 qf0 = *(const f16x8*)(qTb + jt * 32);
    f16x8 qf1 = *(const f16x8*)(qTb + 16 * QL_ + jt * 32);
    #pragma unroll
    for (int fi = 0; fi < 8; ++fi) {
      int row = 16 * fi + l15;
      f16x8 pa = *(const f16x8*)(P_b + (((row << 10) + 64 * jt + 16 * g) ^ ((row & 7) << 4)));
      o[fi][0] = __builtin_amdgcn_mfma_f32_16x16x32_f16(pa, qf0, o[fi][0], 0, 0, 0);
      o[fi][1] = __builtin_amdgcn_mfma_f32_16x16x32_f16(pa, qf1, o[fi][1], 0, 0, 0);
    }
  }
  __syncthreads();   // all P reads done before o_l overwrites region

  #pragma unroll
  for (int fi = 0; fi < 8; ++fi)
    #pragma unroll
    for (int fd = 0; fd < 2; ++fd)
      #pragma unroll
      for (int r = 0; r < 4; ++r)
        o_l[16 * fi + 4 * g + r][32 * w + 16 * fd + l15] = o[fi][fd][r];
  __syncthreads();

  // ---- Epilogue: coalesced f32x4 stores of out[0:3D] -------------------
  #pragma unroll
  for (int s = 0; s < 16; ++s) {
    int idx = tid + 512 * s;                 // 128 rows x 64 f32x4
    int row = idx >> 6, c4 = (idx & 63) * 4;
    size_t rowoff = (size_t)(b * CL_ + i0 + row);
    f32x4 c2q = *(const f32x4*)(&o_l[row][c4]);
    f32x4 cv  = *(const f32x4*)(c + rowoff * D_ + c4);
    f32x4 prod;
    prod[0] = cv[0]*c2q[0]; prod[1] = cv[1]*c2q[1];
    prod[2] = cv[2]*c2q[2]; prod[3] = cv[3]*c2q[3];
    float* ob = out + rowoff * (4 * D_) + c4;
    *(f32x4*)(ob)          = cv;
    *(f32x4*)(ob + D_)     = c2q;
    *(f32x4*)(ob + 2 * D_) = prod;
  }
}

// ------- K2a: bvec[b,:] = softmax_i(mrow[b,:]) ---------------------------
__global__ __launch_bounds__(256) void k2a_bvec(const float* __restrict__ mrow,
                                                float* __restrict__ bvec) {
  __shared__ float red[256];
  int b = blockIdx.x, tid = threadIdx.x;
  f32x4 v = *(const f32x4*)(mrow + b * CL_ + tid * 4);
  float mx = fmaxf(fmaxf(v[0], v[1]), fmaxf(v[2], v[3]));
  red[tid] = mx;
  __syncthreads();
  for (int s = 128; s > 0; s >>= 1) {
    if (tid < s) red[tid] = fmaxf(red[tid], red[tid + s]);
    __syncthreads();
  }
  float gmx = red[0];
  __syncthreads();
  f32x4 e;
  e[0] = __expf(v[0] - gmx); e[1] = __expf(v[1] - gmx);
  e[2] = __expf(v[2] - gmx); e[3] = __expf(v[3] - gmx);
  red[tid] = e[0] + e[1] + e[2] + e[3];
  __syncthreads();
  for (int s = 128; s > 0; s >>= 1) {
    if (tid < s) red[tid] += red[tid + s];
    __syncthreads();
  }
  float inv = 1.0f / red[0];
  e[0] *= inv; e[1] *= inv; e[2] *= inv; e[3] *= inv;
  *(f32x4*)(bvec + b * CL_ + tid * 4) = e;
}

// ------- K2b: part[b,ch,:] = sum_{i in chunk} bvec[i] * c[i,:] -----------
__global__ __launch_bounds__(256) void k2b_part(const float* __restrict__ c,
                                                const float* __restrict__ bvec,
                                                float* __restrict__ part) {
  __shared__ f32x4 pl[4][64];
  int ch = blockIdx.x, b = blockIdx.y, tid = threadIdx.x;
  int ro = tid >> 6, dl = tid & 63;
  const float* cb = c + ((size_t)b * CL_ + ch * 128) * D_;
  const float* bv = bvec + b * CL_ + ch * 128;
  f32x4 acc = (f32x4){0.f, 0.f, 0.f, 0.f};
  for (int i = ro; i < 128; i += 4) {
    float wgt = bv[i];
    f32x4 v = *(const f32x4*)(cb + (size_t)i * D_ + dl * 4);
    acc[0] += wgt * v[0]; acc[1] += wgt * v[1];
    acc[2] += wgt * v[2]; acc[3] += wgt * v[3];
  }
  pl[ro][dl] = acc;
  __syncthreads();
  if (tid < 64) {
    f32x4 s = (pl[0][tid] + pl[1][tid]) + (pl[2][tid] + pl[3][tid]);
    *(f32x4*)(part + ((size_t)(b * 8 + ch)) * D_ + tid * 4) = s;
  }
}

// ------- K2c: q2c[b,:] = sum_ch part[b,ch,:] -----------------------------
__global__ __launch_bounds__(256) void k2c_red(const float* __restrict__ part,
                                               float* __restrict__ q2c) {
  int b = blockIdx.x, d = threadIdx.x;
  float s = 0.f;
  #pragma unroll
  for (int ch = 0; ch < 8; ++ch) s += part[((size_t)(b * 8 + ch)) * D_ + d];
  q2c[b * D_ + d] = s;
}

// ------- K3: out[3D:4D] = c * q2c (broadcast) ----------------------------
__global__ __launch_bounds__(256) void k3_tail(const float* __restrict__ c,
                                               const float* __restrict__ q2c,
                                               float* __restrict__ out) {
  size_t idx = (size_t)blockIdx.x * 256 + threadIdx.x;
  int b   = (int)(idx >> 16);
  int rem = (int)(idx & 65535);
  int i = rem >> 6, d4 = (rem & 63) * 4;
  f32x4 cv = *(const f32x4*)(c + (size_t)(b * CL_ + i) * D_ + d4);
  f32x4 gv = *(const f32x4*)(q2c + b * D_ + d4);
  f32x4 r;
  r[0] = cv[0]*gv[0]; r[1] = cv[1]*gv[1]; r[2] = cv[2]*gv[2]; r[3] = cv[3]*gv[3];
  *(f32x4*)(out + (size_t)(b * CL_ + i) * (4 * D_) + 3 * D_ + d4) = r;
}

extern "C" void kernel_launch(void* const* d_in, const int* in_sizes, int n_in,
                              void* d_out, int out_size, void* d_ws, size_t ws_size,
                              hipStream_t stream) {
  const float* c    = (const float*)d_in[0];
  const float* q    = (const float*)d_in[1];
  const float* w_c  = (const float*)d_in[2];
  const float* w_q  = (const float*)d_in[4];
  const float* w_cq = (const float*)d_in[6];
  float* out = (float*)d_out;
  char* ws = (char*)d_ws;
  f16*   q_h  = (f16*)ws;                       //  8,388,608 B
  f16*   qT_h = (f16*)(ws + 8388608);           //  8,388,608 B
  float* sqv  = (float*)(ws + 16777216);        //     65,536 B
  float* mrow = (float*)(ws + 16842752);        //    131,072 B
  float* bvec = (float*)(ws + 16973824);        //    131,072 B
  float* part = (float*)(ws + 17104896);        //    262,144 B
  float* q2c  = (float*)(ws + 17367040);        //     32,768 B (tot 17,399,808)

  hipLaunchKernelGGL(k0_prep,  dim3(8, 32),  dim3(256), 0, stream,
                     q, w_q, q_h, qT_h, sqv);
  hipLaunchKernelGGL(k1_fused, dim3(256),    dim3(512), 0, stream,
                     c, q_h, qT_h, sqv, w_c, w_cq, out, mrow);
  hipLaunchKernelGGL(k2a_bvec, dim3(32),     dim3(256), 0, stream, mrow, bvec);
  hipLaunchKernelGGL(k2b_part, dim3(8, 32),  dim3(256), 0, stream, c, bvec, part);
  hipLaunchKernelGGL(k2c_red,  dim3(32),     dim3(256), 0, stream, part, q2c);
  hipLaunchKernelGGL(k3_tail,  dim3(8192),   dim3(256), 0, stream, c, q2c, out);
}